// Round 1
// baseline (1093.322 us; speedup 1.0000x reference)
//
#include <hip/hip_runtime.h>
#include <cstdint>
#include <cstddef>

// ---------------------------------------------------------------------------
// Software-exact OCP e4m3fn quant-dequant helper.
// Rounds |v| (assumed <= 448 + tiny) to the e4m3 grid with RTNE:
//   normal step 2^(e-3) for exponent e >= -6, subnormal step 2^-9 below.
// Magic-add trick: (a + 2^(k+23)) - 2^(k+23) rounds a to multiples of 2^k
// with ties-to-even (hardware fp32 add is RNE). Matches ml_dtypes bit-exact.
// ---------------------------------------------------------------------------
__device__ __forceinline__ float qd_e4m3(float v) {
  float a = fabsf(v);
  unsigned u = __float_as_uint(a);
  int e = (int)(u >> 23) - 127;   // a == 0 -> e = -127 -> k clamps, rounds to 0
  int k = e - 3;
  if (k < -9) k = -9;
  float big = __uint_as_float((unsigned)(k + 150) << 23);  // 2^(k+23)
  float r = (a + big) - big;
  return __builtin_copysignf(r, v);
}

// One wave (64 lanes) per 128-element block; 2 elements per lane.
__global__ __launch_bounds__(256) void qd_kernel(const float* __restrict__ src,
                                                 float* __restrict__ dst,
                                                 int nblk) {
  int gid = blockIdx.x * 256 + threadIdx.x;
  int wid = gid >> 6;
  int lane = gid & 63;
  if (wid >= nblk) return;
  size_t off = (size_t)wid * 128 + lane * 2;
  float2 xv = *reinterpret_cast<const float2*>(src + off);
  float m = fmaxf(fabsf(xv.x), fabsf(xv.y));
#pragma unroll
  for (int d = 32; d > 0; d >>= 1) m = fmaxf(m, __shfl_xor(m, d));
  float scale = fmaxf(m / 448.0f, 1e-12f);   // fp32 divide, matches jnp
  float2 o;
  o.x = qd_e4m3(xv.x / scale) * scale;
  o.y = qd_e4m3(xv.y / scale) * scale;
  *reinterpret_cast<float2*>(dst + off) = o;
}

// ---------------------------------------------------------------------------
// fp32 GEMM:  C[M,N] = A[M,K] @ B[K,N] + bias[N]
// 128x128 tile, BK=8, 256 threads, 8x8 micro-tile in 4+4 split.
// M,N multiples of 128; K multiple of 8 (true for all calls here).
// ---------------------------------------------------------------------------
__global__ __launch_bounds__(256) void gemm_bias(const float* __restrict__ A,
                                                 const float* __restrict__ B,
                                                 const float* __restrict__ bias,
                                                 float* __restrict__ C,
                                                 int M, int N, int K) {
  __shared__ float As[8][128];   // transposed A tile: As[k][m]
  __shared__ float Bs[8][128];   // Bs[k][n]
  const int tid = threadIdx.x;
  const int tx = tid & 15, ty = tid >> 4;
  const int row0 = blockIdx.y * 128, col0 = blockIdx.x * 128;
  const int ar = tid >> 1, ac = (tid & 1) * 4;       // A tile 128x8
  const int br = tid >> 5, bc = (tid & 31) * 4;      // B tile 8x128

  float acc[8][8];
#pragma unroll
  for (int i = 0; i < 8; ++i)
#pragma unroll
    for (int j = 0; j < 8; ++j) acc[i][j] = 0.f;

  const float* Ap = A + (size_t)(row0 + ar) * K + ac;
  const float* Bp = B + (size_t)br * N + col0 + bc;

  for (int k0 = 0; k0 < K; k0 += 8) {
    float4 av = *reinterpret_cast<const float4*>(Ap + k0);
    float4 bv = *reinterpret_cast<const float4*>(Bp + (size_t)k0 * N);
    __syncthreads();
    As[ac + 0][ar] = av.x;
    As[ac + 1][ar] = av.y;
    As[ac + 2][ar] = av.z;
    As[ac + 3][ar] = av.w;
    *reinterpret_cast<float4*>(&Bs[br][bc]) = bv;
    __syncthreads();
#pragma unroll
    for (int kk = 0; kk < 8; ++kk) {
      float a[8], b[8];
      *reinterpret_cast<float4*>(a)     = *reinterpret_cast<const float4*>(&As[kk][ty * 4]);
      *reinterpret_cast<float4*>(a + 4) = *reinterpret_cast<const float4*>(&As[kk][64 + ty * 4]);
      *reinterpret_cast<float4*>(b)     = *reinterpret_cast<const float4*>(&Bs[kk][tx * 4]);
      *reinterpret_cast<float4*>(b + 4) = *reinterpret_cast<const float4*>(&Bs[kk][64 + tx * 4]);
#pragma unroll
      for (int i = 0; i < 8; ++i)
#pragma unroll
        for (int j = 0; j < 8; ++j) acc[i][j] += a[i] * b[j];
    }
  }

#pragma unroll
  for (int i = 0; i < 8; ++i) {
    int r = row0 + ((i < 4) ? (ty * 4 + i) : (64 + ty * 4 + (i - 4)));
    float* crow = C + (size_t)r * N;
#pragma unroll
    for (int jj = 0; jj < 2; ++jj) {
      int c = col0 + jj * 64 + tx * 4;
      float4 o;
      o.x = acc[i][jj * 4 + 0] + bias[c + 0];
      o.y = acc[i][jj * 4 + 1] + bias[c + 1];
      o.z = acc[i][jj * 4 + 2] + bias[c + 2];
      o.w = acc[i][jj * 4 + 3] + bias[c + 3];
      *reinterpret_cast<float4*>(crow + c) = o;
    }
  }
}

// ---------------------------------------------------------------------------
// Flash-style fp32 attention. qkv layout: [B=2, S=2048, 3, H=16, Dh=64]
// (row stride 3072; Q at +0, K at +1024, V at +2048, head h at +h*64).
// Grid: (32 q-tiles, 32 b*h). Block: 256 threads = 16 tx * 16 ty,
// each thread owns a 4(q) x 4(k or d) micro-tile of the 64x64 tile.
// Output: out[b, s, h*64 + d]  (the [B,S,H*Dh] layout the ref produces).
// ---------------------------------------------------------------------------
__global__ __launch_bounds__(256) void attn_kernel(const float* __restrict__ qkv,
                                                   float* __restrict__ out) {
  __shared__ float Qst[64][68];  // transposed: Qst[d][q]
  __shared__ float Kst[64][68];  // transposed: Kst[d][k]
  __shared__ float Vs[64][68];   // natural:    Vs[k][d]
  __shared__ float Pst[64][68];  // transposed: Pst[k][q]
  const int tid = threadIdx.x;
  const int tx = tid & 15, ty = tid >> 4;
  const int q0 = blockIdx.x * 64;
  const int bh = blockIdx.y;
  const int b = bh >> 4, h = bh & 15;
  const size_t base = (size_t)b * 2048 * 3072 + (size_t)h * 64;

  // Load Q tile (transposed into LDS), once.
#pragma unroll
  for (int l = 0; l < 4; ++l) {
    int flat = tid + l * 256;
    int r = flat >> 4;
    int d4 = (flat & 15) * 4;
    float4 qv = *reinterpret_cast<const float4*>(qkv + base + (size_t)(q0 + r) * 3072 + d4);
    Qst[d4 + 0][r] = qv.x;
    Qst[d4 + 1][r] = qv.y;
    Qst[d4 + 2][r] = qv.z;
    Qst[d4 + 3][r] = qv.w;
  }

  float m_i[4], l_i[4], acc[4][4];
#pragma unroll
  for (int i = 0; i < 4; ++i) {
    m_i[i] = -__builtin_inff();
    l_i[i] = 0.f;
#pragma unroll
    for (int j = 0; j < 4; ++j) acc[i][j] = 0.f;
  }

  for (int kt = 0; kt < 32; ++kt) {
    __syncthreads();  // previous iteration's PV reads done
    const int k0 = kt * 64;
#pragma unroll
    for (int l = 0; l < 4; ++l) {
      int flat = tid + l * 256;
      int r = flat >> 4;
      int d4 = (flat & 15) * 4;
      const float* kp = qkv + base + 1024 + (size_t)(k0 + r) * 3072 + d4;
      float4 kv = *reinterpret_cast<const float4*>(kp);
      float4 vv = *reinterpret_cast<const float4*>(kp + 1024);
      Kst[d4 + 0][r] = kv.x;
      Kst[d4 + 1][r] = kv.y;
      Kst[d4 + 2][r] = kv.z;
      Kst[d4 + 3][r] = kv.w;
      *reinterpret_cast<float4*>(&Vs[r][d4]) = vv;
    }
    __syncthreads();

    // scores: s[i][j] = sum_d Q[q0+ty*4+i][d] * K[k0+tx*4+j][d]
    float s[4][4];
#pragma unroll
    for (int i = 0; i < 4; ++i)
#pragma unroll
      for (int j = 0; j < 4; ++j) s[i][j] = 0.f;
    for (int d = 0; d < 64; ++d) {
      float4 q4 = *reinterpret_cast<const float4*>(&Qst[d][ty * 4]);
      float4 k4 = *reinterpret_cast<const float4*>(&Kst[d][tx * 4]);
      float qa[4] = {q4.x, q4.y, q4.z, q4.w};
      float ka[4] = {k4.x, k4.y, k4.z, k4.w};
#pragma unroll
      for (int i = 0; i < 4; ++i)
#pragma unroll
        for (int j = 0; j < 4; ++j) s[i][j] += qa[i] * ka[j];
    }

    // online softmax update (per q-row, reduced across the 16 tx lanes)
    float p[4][4];
#pragma unroll
    for (int i = 0; i < 4; ++i) {
#pragma unroll
      for (int j = 0; j < 4; ++j) s[i][j] *= 0.125f;  // 1/sqrt(64), exact
      float mt = fmaxf(fmaxf(s[i][0], s[i][1]), fmaxf(s[i][2], s[i][3]));
#pragma unroll
      for (int d = 1; d < 16; d <<= 1) mt = fmaxf(mt, __shfl_xor(mt, d));
      float mn = fmaxf(m_i[i], mt);
      float corr = expf(m_i[i] - mn);
      float rs = 0.f;
#pragma unroll
      for (int j = 0; j < 4; ++j) {
        float pv = expf(s[i][j] - mn);
        p[i][j] = pv;
        rs += pv;
      }
#pragma unroll
      for (int d = 1; d < 16; d <<= 1) rs += __shfl_xor(rs, d);
      m_i[i] = mn;
      l_i[i] = l_i[i] * corr + rs;
#pragma unroll
      for (int j = 0; j < 4; ++j) acc[i][j] *= corr;
    }

    // publish probs (transposed) for the PV stage
#pragma unroll
    for (int j = 0; j < 4; ++j)
#pragma unroll
      for (int i = 0; i < 4; ++i) Pst[tx * 4 + j][ty * 4 + i] = p[i][j];
    __syncthreads();

    // PV: acc[i][j] += sum_k P[q][k] * V[k][d],  d = tx*4+j
    for (int k = 0; k < 64; ++k) {
      float4 p4 = *reinterpret_cast<const float4*>(&Pst[k][ty * 4]);
      float4 v4 = *reinterpret_cast<const float4*>(&Vs[k][tx * 4]);
      float pa[4] = {p4.x, p4.y, p4.z, p4.w};
      float va[4] = {v4.x, v4.y, v4.z, v4.w};
#pragma unroll
      for (int i = 0; i < 4; ++i)
#pragma unroll
        for (int j = 0; j < 4; ++j) acc[i][j] += pa[i] * va[j];
    }
  }

  // epilogue: normalize and store [B,S,H*Dh]
#pragma unroll
  for (int i = 0; i < 4; ++i) {
    float inv = 1.0f / l_i[i];
    float4 o;
    o.x = acc[i][0] * inv;
    o.y = acc[i][1] * inv;
    o.z = acc[i][2] * inv;
    o.w = acc[i][3] * inv;
    size_t orow = ((size_t)b * 2048 + q0 + ty * 4 + i) * 1024 + h * 64 + tx * 4;
    *reinterpret_cast<float4*>(out + orow) = o;
  }
}

// ---------------------------------------------------------------------------
// Orchestration. Workspace layout (80 MB total):
//   [ 0,16) MB : xq   (quantized x; later reused for quantized attn output)
//   [16,28) MB : Wq_qkv
//   [28,32) MB : Wq_out
//   [32,80) MB : qkv  [4096, 3072]
// attn output goes directly into d_out (16 MB), then is quant-dequanted into
// the reused xq buffer before the final projection overwrites d_out.
// ---------------------------------------------------------------------------
extern "C" void kernel_launch(void* const* d_in, const int* in_sizes, int n_in,
                              void* d_out, int out_size, void* d_ws, size_t ws_size,
                              hipStream_t stream) {
  const float* x     = (const float*)d_in[0];   // [2,2048,1024]
  const float* W_qkv = (const float*)d_in[1];   // [1024,3072]
  const float* b_qkv = (const float*)d_in[2];   // [3072]
  const float* W_out = (const float*)d_in[3];   // [1024,1024]
  const float* b_out = (const float*)d_in[4];   // [1024]
  float* y = (float*)d_out;                     // [2,2048,1024] fp32

  char* ws = (char*)d_ws;
  float* xq    = (float*)(ws);
  float* wqkvq = (float*)(ws + (size_t)(16u << 20));
  float* woutq = (float*)(ws + (size_t)(28u << 20));
  float* qkv   = (float*)(ws + (size_t)(32u << 20));

  // 1. blockwise e4m3 quant-dequant of activations and weights
  qd_kernel<<<8192, 256, 0, stream>>>(x, xq, 32768);        // 4096*1024/128
  qd_kernel<<<6144, 256, 0, stream>>>(W_qkv, wqkvq, 24576); // 1024*3072/128
  qd_kernel<<<2048, 256, 0, stream>>>(W_out, woutq, 8192);  // 1024*1024/128

  // 2. QKV projection: [4096,1024] @ [1024,3072] + b
  gemm_bias<<<dim3(24, 32), 256, 0, stream>>>(xq, wqkvq, b_qkv, qkv, 4096, 3072, 1024);

  // 3. multi-head attention -> d_out as [B,S,H*Dh]
  attn_kernel<<<dim3(32, 32), 256, 0, stream>>>(qkv, y);

  // 4. quant-dequant attention output (reuse xq buffer)
  qd_kernel<<<8192, 256, 0, stream>>>(y, xq, 32768);

  // 5. output projection: [4096,1024] @ [1024,1024] + b -> d_out
  gemm_bias<<<dim3(8, 32), 256, 0, stream>>>(xq, woutq, b_out, y, 4096, 1024, 1024);
}

// Round 2
// 817.115 us; speedup vs baseline: 1.3380x; 1.3380x over previous
//
#include <hip/hip_runtime.h>
#include <cstdint>
#include <cstddef>

typedef __attribute__((ext_vector_type(8))) short bfrag;   // 8 bf16 (4 VGPR)
typedef __attribute__((ext_vector_type(4))) float f4;      // MFMA C/D
typedef __attribute__((ext_vector_type(4))) unsigned short us4;

#define MFMA16(a, b, c) __builtin_amdgcn_mfma_f32_16x16x32_bf16(a, b, c, 0, 0, 0)

// ---------------------------------------------------------------------------
// fp32 -> bf16 RNE, and hi/lo split helpers
// ---------------------------------------------------------------------------
__device__ __forceinline__ unsigned short f2bf(float x) {
  unsigned u = __float_as_uint(x);
  u += 0x7fffu + ((u >> 16) & 1u);
  return (unsigned short)(u >> 16);
}
__device__ __forceinline__ float bf2f(unsigned short h) {
  return __uint_as_float(((unsigned)h) << 16);
}

// ---------------------------------------------------------------------------
// Software-exact OCP e4m3fn quant-dequant (RTNE via magic-add; matches
// ml_dtypes bit-exact incl. subnormal grid 2^-9 and 448-saturation region).
// ---------------------------------------------------------------------------
__device__ __forceinline__ float qd_e4m3(float v) {
  float a = fabsf(v);
  unsigned u = __float_as_uint(a);
  int e = (int)(u >> 23) - 127;
  int k = e - 3;
  if (k < -9) k = -9;
  float big = __uint_as_float((unsigned)(k + 150) << 23);  // 2^(k+23)
  float r = (a + big) - big;
  return __builtin_copysignf(r, v);
}

// One wave per 128-element block; 2 elements per lane.
__global__ __launch_bounds__(256) void qd_kernel(const float* __restrict__ src,
                                                 float* __restrict__ dst,
                                                 int nblk) {
  int gid = blockIdx.x * 256 + threadIdx.x;
  int wid = gid >> 6;
  int lane = gid & 63;
  if (wid >= nblk) return;
  size_t off = (size_t)wid * 128 + lane * 2;
  float2 xv = *reinterpret_cast<const float2*>(src + off);
  float m = fmaxf(fabsf(xv.x), fabsf(xv.y));
#pragma unroll
  for (int d = 32; d > 0; d >>= 1) m = fmaxf(m, __shfl_xor(m, d));
  float scale = fmaxf(m / 448.0f, 1e-12f);
  float2 o;
  o.x = qd_e4m3(xv.x / scale) * scale;
  o.y = qd_e4m3(xv.y / scale) * scale;
  *reinterpret_cast<float2*>(dst + off) = o;
}

// ---------------------------------------------------------------------------
// fp32 GEMM (kept for the output projection):
// C[M,N] = A[M,K] @ B[K,N] + bias[N]; 128x128 tile, BK=8, 256 thr, 8x8 micro.
// ---------------------------------------------------------------------------
__global__ __launch_bounds__(256) void gemm_bias(const float* __restrict__ A,
                                                 const float* __restrict__ B,
                                                 const float* __restrict__ bias,
                                                 float* __restrict__ C,
                                                 int M, int N, int K) {
  __shared__ float As[8][128];
  __shared__ float Bs[8][128];
  const int tid = threadIdx.x;
  const int tx = tid & 15, ty = tid >> 4;
  const int row0 = blockIdx.y * 128, col0 = blockIdx.x * 128;
  const int ar = tid >> 1, ac = (tid & 1) * 4;
  const int br = tid >> 5, bc = (tid & 31) * 4;

  float acc[8][8];
#pragma unroll
  for (int i = 0; i < 8; ++i)
#pragma unroll
    for (int j = 0; j < 8; ++j) acc[i][j] = 0.f;

  const float* Ap = A + (size_t)(row0 + ar) * K + ac;
  const float* Bp = B + (size_t)br * N + col0 + bc;

  for (int k0 = 0; k0 < K; k0 += 8) {
    float4 av = *reinterpret_cast<const float4*>(Ap + k0);
    float4 bv = *reinterpret_cast<const float4*>(Bp + (size_t)k0 * N);
    __syncthreads();
    As[ac + 0][ar] = av.x;
    As[ac + 1][ar] = av.y;
    As[ac + 2][ar] = av.z;
    As[ac + 3][ar] = av.w;
    *reinterpret_cast<float4*>(&Bs[br][bc]) = bv;
    __syncthreads();
#pragma unroll
    for (int kk = 0; kk < 8; ++kk) {
      float a[8], b[8];
      *reinterpret_cast<float4*>(a)     = *reinterpret_cast<const float4*>(&As[kk][ty * 4]);
      *reinterpret_cast<float4*>(a + 4) = *reinterpret_cast<const float4*>(&As[kk][64 + ty * 4]);
      *reinterpret_cast<float4*>(b)     = *reinterpret_cast<const float4*>(&Bs[kk][tx * 4]);
      *reinterpret_cast<float4*>(b + 4) = *reinterpret_cast<const float4*>(&Bs[kk][64 + tx * 4]);
#pragma unroll
      for (int i = 0; i < 8; ++i)
#pragma unroll
        for (int j = 0; j < 8; ++j) acc[i][j] += a[i] * b[j];
    }
  }

#pragma unroll
  for (int i = 0; i < 8; ++i) {
    int r = row0 + ((i < 4) ? (ty * 4 + i) : (64 + ty * 4 + (i - 4)));
    float* crow = C + (size_t)r * N;
#pragma unroll
    for (int jj = 0; jj < 2; ++jj) {
      int c = col0 + jj * 64 + tx * 4;
      float4 o;
      o.x = acc[i][jj * 4 + 0] + bias[c + 0];
      o.y = acc[i][jj * 4 + 1] + bias[c + 1];
      o.z = acc[i][jj * 4 + 2] + bias[c + 2];
      o.w = acc[i][jj * 4 + 3] + bias[c + 3];
      *reinterpret_cast<float4*>(crow + c) = o;
    }
  }
}

// ---------------------------------------------------------------------------
// Same fp32 GEMM, but epilogue writes (acc+bias) as split bf16 hi/lo arrays
// (for the QKV projection: attention consumes hi/lo directly).
// ---------------------------------------------------------------------------
__global__ __launch_bounds__(256) void gemm_bias_split(const float* __restrict__ A,
                                                       const float* __restrict__ B,
                                                       const float* __restrict__ bias,
                                                       unsigned short* __restrict__ Ch,
                                                       unsigned short* __restrict__ Cl,
                                                       int M, int N, int K) {
  __shared__ float As[8][128];
  __shared__ float Bs[8][128];
  const int tid = threadIdx.x;
  const int tx = tid & 15, ty = tid >> 4;
  const int row0 = blockIdx.y * 128, col0 = blockIdx.x * 128;
  const int ar = tid >> 1, ac = (tid & 1) * 4;
  const int br = tid >> 5, bc = (tid & 31) * 4;

  float acc[8][8];
#pragma unroll
  for (int i = 0; i < 8; ++i)
#pragma unroll
    for (int j = 0; j < 8; ++j) acc[i][j] = 0.f;

  const float* Ap = A + (size_t)(row0 + ar) * K + ac;
  const float* Bp = B + (size_t)br * N + col0 + bc;

  for (int k0 = 0; k0 < K; k0 += 8) {
    float4 av = *reinterpret_cast<const float4*>(Ap + k0);
    float4 bv = *reinterpret_cast<const float4*>(Bp + (size_t)k0 * N);
    __syncthreads();
    As[ac + 0][ar] = av.x;
    As[ac + 1][ar] = av.y;
    As[ac + 2][ar] = av.z;
    As[ac + 3][ar] = av.w;
    *reinterpret_cast<float4*>(&Bs[br][bc]) = bv;
    __syncthreads();
#pragma unroll
    for (int kk = 0; kk < 8; ++kk) {
      float a[8], b[8];
      *reinterpret_cast<float4*>(a)     = *reinterpret_cast<const float4*>(&As[kk][ty * 4]);
      *reinterpret_cast<float4*>(a + 4) = *reinterpret_cast<const float4*>(&As[kk][64 + ty * 4]);
      *reinterpret_cast<float4*>(b)     = *reinterpret_cast<const float4*>(&Bs[kk][tx * 4]);
      *reinterpret_cast<float4*>(b + 4) = *reinterpret_cast<const float4*>(&Bs[kk][64 + tx * 4]);
#pragma unroll
      for (int i = 0; i < 8; ++i)
#pragma unroll
        for (int j = 0; j < 8; ++j) acc[i][j] += a[i] * b[j];
    }
  }

#pragma unroll
  for (int i = 0; i < 8; ++i) {
    int r = row0 + ((i < 4) ? (ty * 4 + i) : (64 + ty * 4 + (i - 4)));
    size_t rb = (size_t)r * N;
#pragma unroll
    for (int jj = 0; jj < 2; ++jj) {
      int c = col0 + jj * 64 + tx * 4;
      us4 h4, l4;
#pragma unroll
      for (int k = 0; k < 4; ++k) {
        float o = acc[i][jj * 4 + k] + bias[c + k];
        unsigned short hh = f2bf(o);
        h4[k] = hh;
        l4[k] = f2bf(o - bf2f(hh));
      }
      *reinterpret_cast<us4*>(Ch + rb + c) = h4;
      *reinterpret_cast<us4*>(Cl + rb + c) = l4;
    }
  }
}

// ---------------------------------------------------------------------------
// MFMA flash attention, split-bf16 (3-pass) for both QK^T and PV.
// qkvh/qkvl: [B*S=4096][3072] bf16 hi/lo of (x@Wqkv + b). Q at col 0,
// K at 1024, V at 2048; head h at +h*64.
// Grid (S/64=32, B*H=32), 256 threads = 4 waves; wave w owns 16 q-rows.
// Fragment layouts (16x16x32 bf16): A row=l&15,k=(l>>4)*8+e; B col=l&15,
// same k; C/D col=l&15, row=(l>>4)*4+reg.
// ---------------------------------------------------------------------------
__global__ __launch_bounds__(256) void attn_mfma(const unsigned short* __restrict__ qkvh,
                                                 const unsigned short* __restrict__ qkvl,
                                                 float* __restrict__ out) {
  __shared__ __align__(16) unsigned short Vth[64][72];  // V^T hi: [d][kpos]
  __shared__ __align__(16) unsigned short Vtl[64][72];
  __shared__ __align__(16) unsigned short Ph[4][16][72];  // per-wave P hi: [q][kpos]
  __shared__ __align__(16) unsigned short Pl[4][16][72];
  const int tid = threadIdx.x;
  const int w = tid >> 6, l = tid & 63;
  const int lr = l & 15, lg = l >> 4;
  const int q0 = blockIdx.x * 64;
  const int b = blockIdx.y >> 4, h = blockIdx.y & 15;
  const size_t bbase = (size_t)b * 2048;

  // Q fragments for this wave's 16 rows (hoisted out of the K loop)
  const size_t qrow = (bbase + q0 + w * 16 + lr) * 3072 + h * 64;
  bfrag qh[2], ql[2];
#pragma unroll
  for (int dc = 0; dc < 2; ++dc) {
    qh[dc] = *reinterpret_cast<const bfrag*>(qkvh + qrow + dc * 32 + lg * 8);
    ql[dc] = *reinterpret_cast<const bfrag*>(qkvl + qrow + dc * 32 + lg * 8);
  }

  f4 oacc[4];
  float m_i[4], l_i[4];
#pragma unroll
  for (int i = 0; i < 4; ++i) {
    m_i[i] = -1e30f;
    l_i[i] = 0.f;
#pragma unroll
    for (int j = 0; j < 4; ++j) oacc[i][j] = 0.f;
  }

  for (int kt = 0; kt < 32; ++kt) {
    const size_t krow = bbase + (size_t)kt * 64;
    __syncthreads();  // all waves done with previous V tile
    {  // stage V^T: wave w covers d = w*16..w*16+15, lane l -> kpos l
      const size_t vrow = (krow + l) * 3072 + 2048 + h * 64 + w * 16;
      bfrag vh0 = *reinterpret_cast<const bfrag*>(qkvh + vrow);
      bfrag vh1 = *reinterpret_cast<const bfrag*>(qkvh + vrow + 8);
      bfrag vl0 = *reinterpret_cast<const bfrag*>(qkvl + vrow);
      bfrag vl1 = *reinterpret_cast<const bfrag*>(qkvl + vrow + 8);
#pragma unroll
      for (int j = 0; j < 8; ++j) {
        Vth[w * 16 + j][l]     = (unsigned short)vh0[j];
        Vth[w * 16 + 8 + j][l] = (unsigned short)vh1[j];
        Vtl[w * 16 + j][l]     = (unsigned short)vl0[j];
        Vtl[w * 16 + 8 + j][l] = (unsigned short)vl1[j];
      }
    }
    __syncthreads();

    // S = Q·K^T (16 q-rows x 64 kpos), split-bf16 3-pass
    f4 sacc[4];
#pragma unroll
    for (int ks = 0; ks < 4; ++ks)
#pragma unroll
      for (int j = 0; j < 4; ++j) sacc[ks][j] = 0.f;
#pragma unroll
    for (int ks = 0; ks < 4; ++ks) {
      const size_t kr = (krow + ks * 16 + lr) * 3072 + 1024 + h * 64;
#pragma unroll
      for (int dc = 0; dc < 2; ++dc) {
        bfrag kh = *reinterpret_cast<const bfrag*>(qkvh + kr + dc * 32 + lg * 8);
        bfrag kl = *reinterpret_cast<const bfrag*>(qkvl + kr + dc * 32 + lg * 8);
        sacc[ks] = MFMA16(qh[dc], kh, sacc[ks]);
        sacc[ks] = MFMA16(qh[dc], kl, sacc[ks]);
        sacc[ks] = MFMA16(ql[dc], kh, sacc[ks]);
      }
    }

    // online softmax; this thread's q-rows are lg*4 + r, cols ks*16 + lr
#pragma unroll
    for (int r = 0; r < 4; ++r) {
      float s0 = sacc[0][r] * 0.125f, s1 = sacc[1][r] * 0.125f;
      float s2 = sacc[2][r] * 0.125f, s3 = sacc[3][r] * 0.125f;
      float mt = fmaxf(fmaxf(s0, s1), fmaxf(s2, s3));
#pragma unroll
      for (int d = 1; d < 16; d <<= 1) mt = fmaxf(mt, __shfl_xor(mt, d));
      float mn = fmaxf(m_i[r], mt);
      float corr = __expf(m_i[r] - mn);
      float p0 = __expf(s0 - mn), p1 = __expf(s1 - mn);
      float p2 = __expf(s2 - mn), p3 = __expf(s3 - mn);
      float rs = (p0 + p1) + (p2 + p3);
#pragma unroll
      for (int d = 1; d < 16; d <<= 1) rs += __shfl_xor(rs, d);
      m_i[r] = mn;
      l_i[r] = l_i[r] * corr + rs;
#pragma unroll
      for (int ds = 0; ds < 4; ++ds) oacc[ds][r] *= corr;
      // publish P (split) to this wave's LDS strip
      float pa[4] = {p0, p1, p2, p3};
#pragma unroll
      for (int ks = 0; ks < 4; ++ks) {
        unsigned short hh = f2bf(pa[ks]);
        Ph[w][lg * 4 + r][ks * 16 + lr] = hh;
        Pl[w][lg * 4 + r][ks * 16 + lr] = f2bf(pa[ks] - bf2f(hh));
      }
    }

    // PV: O[16 q][64 d] += P · V  (wave-local P, shared V^T)
#pragma unroll
    for (int kc = 0; kc < 2; ++kc) {
      bfrag pah = *reinterpret_cast<const bfrag*>(&Ph[w][lr][kc * 32 + lg * 8]);
      bfrag pal = *reinterpret_cast<const bfrag*>(&Pl[w][lr][kc * 32 + lg * 8]);
#pragma unroll
      for (int ds = 0; ds < 4; ++ds) {
        bfrag vbh = *reinterpret_cast<const bfrag*>(&Vth[ds * 16 + lr][kc * 32 + lg * 8]);
        bfrag vbl = *reinterpret_cast<const bfrag*>(&Vtl[ds * 16 + lr][kc * 32 + lg * 8]);
        oacc[ds] = MFMA16(pah, vbh, oacc[ds]);
        oacc[ds] = MFMA16(pah, vbl, oacc[ds]);
        oacc[ds] = MFMA16(pal, vbh, oacc[ds]);
      }
    }
  }

  // epilogue: normalize, store fp32 [B,S,H*Dh]
#pragma unroll
  for (int r = 0; r < 4; ++r) {
    float inv = 1.0f / l_i[r];
    size_t orow = (bbase + q0 + w * 16 + lg * 4 + r) * 1024 + h * 64 + lr;
#pragma unroll
    for (int ds = 0; ds < 4; ++ds) out[orow + ds * 16] = oacc[ds][r] * inv;
  }
}

// ---------------------------------------------------------------------------
// Orchestration. Workspace (80 MiB, same budget as round 1):
//   [ 0,16) MiB : xq    (quantized x; reused for quantized attn output)
//   [16,28) MiB : Wq_qkv
//   [28,32) MiB : Wq_out
//   [32,56) MiB : qkvh  [4096,3072] bf16
//   [56,80) MiB : qkvl  [4096,3072] bf16
// ---------------------------------------------------------------------------
extern "C" void kernel_launch(void* const* d_in, const int* in_sizes, int n_in,
                              void* d_out, int out_size, void* d_ws, size_t ws_size,
                              hipStream_t stream) {
  const float* x     = (const float*)d_in[0];
  const float* W_qkv = (const float*)d_in[1];
  const float* b_qkv = (const float*)d_in[2];
  const float* W_out = (const float*)d_in[3];
  const float* b_out = (const float*)d_in[4];
  float* y = (float*)d_out;

  char* ws = (char*)d_ws;
  float* xq    = (float*)(ws);
  float* wqkvq = (float*)(ws + (size_t)(16u << 20));
  float* woutq = (float*)(ws + (size_t)(28u << 20));
  unsigned short* qkvh = (unsigned short*)(ws + (size_t)(32u << 20));
  unsigned short* qkvl = (unsigned short*)(ws + (size_t)(56u << 20));

  // 1. blockwise e4m3 quant-dequant
  qd_kernel<<<8192, 256, 0, stream>>>(x, xq, 32768);
  qd_kernel<<<6144, 256, 0, stream>>>(W_qkv, wqkvq, 24576);
  qd_kernel<<<2048, 256, 0, stream>>>(W_out, woutq, 8192);

  // 2. QKV projection -> split bf16 hi/lo
  gemm_bias_split<<<dim3(24, 32), 256, 0, stream>>>(xq, wqkvq, b_qkv, qkvh, qkvl,
                                                    4096, 3072, 1024);

  // 3. MFMA flash attention -> d_out [B,S,H*Dh] fp32
  attn_mfma<<<dim3(32, 32), 256, 0, stream>>>(qkvh, qkvl, y);

  // 4. quant-dequant attention output (reuse xq)
  qd_kernel<<<8192, 256, 0, stream>>>(y, xq, 32768);

  // 5. output projection
  gemm_bias<<<dim3(8, 32), 256, 0, stream>>>(xq, woutq, b_out, y, 4096, 1024, 1024);
}

// Round 3
// 482.095 us; speedup vs baseline: 2.2679x; 1.6949x over previous
//
#include <hip/hip_runtime.h>
#include <cstdint>
#include <cstddef>

typedef __attribute__((ext_vector_type(8))) short bfrag;   // 8 bf16 (4 VGPR)
typedef __attribute__((ext_vector_type(4))) float f4;      // MFMA C/D
typedef __attribute__((ext_vector_type(4))) unsigned short us4;

#define MFMA16(a, b, c) __builtin_amdgcn_mfma_f32_16x16x32_bf16(a, b, c, 0, 0, 0)

// ---------------------------------------------------------------------------
// fp32 -> bf16 RNE, and hi/lo split helpers
// ---------------------------------------------------------------------------
__device__ __forceinline__ unsigned short f2bf(float x) {
  unsigned u = __float_as_uint(x);
  u += 0x7fffu + ((u >> 16) & 1u);
  return (unsigned short)(u >> 16);
}
__device__ __forceinline__ float bf2f(unsigned short h) {
  return __uint_as_float(((unsigned)h) << 16);
}

// ---------------------------------------------------------------------------
// Software-exact OCP e4m3fn rounding (RTNE via magic-add; matches ml_dtypes
// bit-exact incl. subnormal grid 2^-9 and the 448-saturation region).
// ---------------------------------------------------------------------------
__device__ __forceinline__ float qd_e4m3(float v) {
  float a = fabsf(v);
  unsigned u = __float_as_uint(a);
  int e = (int)(u >> 23) - 127;
  int k = e - 3;
  if (k < -9) k = -9;
  float big = __uint_as_float((unsigned)(k + 150) << 23);  // 2^(k+23)
  float r = (a + big) - big;
  return __builtin_copysignf(r, v);
}

// ---------------------------------------------------------------------------
// Activation quant: per 128-block, emit e4m3 CODES as bf16 (exact) + scale.
// One wave per block, 2 elements/lane. s is flat [M * K/128].
// ---------------------------------------------------------------------------
__global__ __launch_bounds__(256) void quant_x(const float* __restrict__ src,
                                               unsigned short* __restrict__ q,
                                               float* __restrict__ s,
                                               int nblk) {
  int gid = blockIdx.x * 256 + threadIdx.x;
  int wid = gid >> 6;
  int lane = gid & 63;
  if (wid >= nblk) return;
  size_t off = (size_t)wid * 128 + lane * 2;
  float2 xv = *reinterpret_cast<const float2*>(src + off);
  float m = fmaxf(fabsf(xv.x), fabsf(xv.y));
#pragma unroll
  for (int d = 32; d > 0; d >>= 1) m = fmaxf(m, __shfl_xor(m, d));
  float scale = fmaxf(m / 448.0f, 1e-12f);
  unsigned short q0 = f2bf(qd_e4m3(xv.x / scale));  // exact: e4m3 ⊂ bf16
  unsigned short q1 = f2bf(qd_e4m3(xv.y / scale));
  *reinterpret_cast<unsigned*>(q + off) = (unsigned)q0 | ((unsigned)q1 << 16);
  if (lane == 0) s[wid] = scale;
}

// ---------------------------------------------------------------------------
// Weight quant + dequant + hi/lo split + TRANSPOSE: W[K,N] (blocks along N)
// -> WTh/WTl[N,K] bf16. Tile: 64 k-rows x 128 n-cols per workgroup.
// ---------------------------------------------------------------------------
__global__ __launch_bounds__(256) void quant_w_t(const float* __restrict__ W,
                                                 unsigned short* __restrict__ WTh,
                                                 unsigned short* __restrict__ WTl,
                                                 int K, int N) {
  __shared__ __align__(16) unsigned short Ht[128][72];
  __shared__ __align__(16) unsigned short Lt[128][72];
  const int tid = threadIdx.x;
  const int w = tid >> 6, l = tid & 63;
  const int k0 = blockIdx.y * 64, n0 = blockIdx.x * 128;
#pragma unroll 4
  for (int i = 0; i < 16; ++i) {
    int kl = w * 16 + i;
    float2 xv = *reinterpret_cast<const float2*>(&W[(size_t)(k0 + kl) * N + n0 + l * 2]);
    float m = fmaxf(fabsf(xv.x), fabsf(xv.y));
#pragma unroll
    for (int d = 32; d > 0; d >>= 1) m = fmaxf(m, __shfl_xor(m, d));
    float scale = fmaxf(m / 448.0f, 1e-12f);
    float d0 = qd_e4m3(xv.x / scale) * scale;
    float d1 = qd_e4m3(xv.y / scale) * scale;
    unsigned short h0 = f2bf(d0), h1 = f2bf(d1);
    Ht[l * 2][kl] = h0;
    Ht[l * 2 + 1][kl] = h1;
    Lt[l * 2][kl] = f2bf(d0 - bf2f(h0));
    Lt[l * 2 + 1][kl] = f2bf(d1 - bf2f(h1));
  }
  __syncthreads();
  // write out: thread t -> array (t>>7), n-row (t&127): 64 k-contig shorts
  const int arr = tid >> 7, n = tid & 127;
  const unsigned short(*T)[72] = arr ? Lt : Ht;
  unsigned short* dst = (arr ? WTl : WTh) + (size_t)(n0 + n) * K + k0;
#pragma unroll
  for (int j = 0; j < 8; ++j)
    *reinterpret_cast<bfrag*>(dst + j * 8) = *reinterpret_cast<const bfrag*>(&T[n][j * 8]);
}

// ---------------------------------------------------------------------------
// Quantization-aware MFMA GEMM:
//   C[M,N] = sum_kb s_x[m,kb] * ( sum_{k in kb} Aq[m,k]*(WTh[n,k]+WTl[n,k]) ) + bias[n]
// Aq: e4m3 codes in bf16 (EXACT). WTh/WTl: [N,K] split-bf16 dequant weights.
// 128x128 tile, BK=64, 256 thr = 4 waves (2x2), wave tile 64x64 (4x4 frags).
// Per-k-block (128) scale applied via seg accumulator every 2 iterations.
// SPLIT=true: emit hi/lo bf16 (for attention); else fp32.
// ---------------------------------------------------------------------------
template <bool SPLIT>
__global__ __launch_bounds__(256, 2) void gemm_q(const unsigned short* __restrict__ Aq,
                                                 const float* __restrict__ As,
                                                 const unsigned short* __restrict__ WTh,
                                                 const unsigned short* __restrict__ WTl,
                                                 const float* __restrict__ bias,
                                                 float* __restrict__ Cf,
                                                 unsigned short* __restrict__ Ch,
                                                 unsigned short* __restrict__ Cl,
                                                 int M, int N, int K) {
  __shared__ __align__(16) unsigned short Al[128][72];
  __shared__ __align__(16) unsigned short Bh[128][72];
  __shared__ __align__(16) unsigned short Bl[128][72];
  __shared__ float Ss[128][8];
  const int tid = threadIdx.x;
  const int w = tid >> 6, l = tid & 63;
  const int lr = l & 15, lg = l >> 4;
  // XCD-aware bijective swizzle (grid sizes here are multiples of 8)
  const int nbx = N >> 7;
  const int nwg = nbx * (M >> 7);
  const int q8 = nwg >> 3;
  const int swz = ((int)blockIdx.x & 7) * q8 + ((int)blockIdx.x >> 3);
  const int row0 = (swz / nbx) << 7, col0 = (swz % nbx) << 7;
  const int wr = (w >> 1) * 64, wc = (w & 1) * 64;

  {  // stage per-row k-block scales once (K=1024 -> 8 blocks)
    int r = tid >> 1, c0 = (tid & 1) * 4;
    *reinterpret_cast<float4*>(&Ss[r][c0]) =
        *reinterpret_cast<const float4*>(&As[(size_t)(row0 + r) * 8 + c0]);
  }

  f4 acc[4][4], seg[4][4];
#pragma unroll
  for (int i = 0; i < 4; ++i)
#pragma unroll
    for (int j = 0; j < 4; ++j)
#pragma unroll
      for (int c = 0; c < 4; ++c) {
        acc[i][j][c] = 0.f;
        seg[i][j][c] = 0.f;
      }

  const int sr = tid >> 1, sko = (tid & 1) * 32;
  const unsigned short* gA = Aq + (size_t)(row0 + sr) * K + sko;
  const unsigned short* gH = WTh + (size_t)(col0 + sr) * K + sko;
  const unsigned short* gL = WTl + (size_t)(col0 + sr) * K + sko;

  const int niter = K >> 6;
  for (int it = 0; it < niter; ++it) {
    const int k0 = it << 6;
    __syncthreads();  // previous compute done (also covers Ss staging at it=0)
#pragma unroll
    for (int j = 0; j < 4; ++j) {
      *reinterpret_cast<bfrag*>(&Al[sr][sko + j * 8]) =
          *reinterpret_cast<const bfrag*>(gA + k0 + j * 8);
      *reinterpret_cast<bfrag*>(&Bh[sr][sko + j * 8]) =
          *reinterpret_cast<const bfrag*>(gH + k0 + j * 8);
      *reinterpret_cast<bfrag*>(&Bl[sr][sko + j * 8]) =
          *reinterpret_cast<const bfrag*>(gL + k0 + j * 8);
    }
    __syncthreads();

#pragma unroll
    for (int ks = 0; ks < 2; ++ks) {
      bfrag af[4];
#pragma unroll
      for (int mf = 0; mf < 4; ++mf)
        af[mf] = *reinterpret_cast<const bfrag*>(&Al[wr + mf * 16 + lr][ks * 32 + lg * 8]);
#pragma unroll
      for (int nf = 0; nf < 4; ++nf) {
        bfrag bh = *reinterpret_cast<const bfrag*>(&Bh[wc + nf * 16 + lr][ks * 32 + lg * 8]);
        bfrag bl = *reinterpret_cast<const bfrag*>(&Bl[wc + nf * 16 + lr][ks * 32 + lg * 8]);
#pragma unroll
        for (int mf = 0; mf < 4; ++mf) {
          seg[mf][nf] = MFMA16(af[mf], bh, seg[mf][nf]);
          seg[mf][nf] = MFMA16(af[mf], bl, seg[mf][nf]);
        }
      }
    }

    if (it & 1) {  // finished a 128-wide quant block: fold with exact scale
      const int kb = it >> 1;
#pragma unroll
      for (int mf = 0; mf < 4; ++mf) {
        float sv[4];
#pragma unroll
        for (int r = 0; r < 4; ++r) sv[r] = Ss[wr + mf * 16 + lg * 4 + r][kb];
#pragma unroll
        for (int nf = 0; nf < 4; ++nf)
#pragma unroll
          for (int r = 0; r < 4; ++r) {
            acc[mf][nf][r] += sv[r] * seg[mf][nf][r];
            seg[mf][nf][r] = 0.f;
          }
      }
    }
  }

  // epilogue
#pragma unroll
  for (int mf = 0; mf < 4; ++mf) {
#pragma unroll
    for (int r = 0; r < 4; ++r) {
      const int m = row0 + wr + mf * 16 + lg * 4 + r;
#pragma unroll
      for (int nf = 0; nf < 4; ++nf) {
        const int col = col0 + wc + nf * 16 + lr;
        float o = acc[mf][nf][r] + bias[col];
        if (SPLIT) {
          unsigned short hh = f2bf(o);
          Ch[(size_t)m * N + col] = hh;
          Cl[(size_t)m * N + col] = f2bf(o - bf2f(hh));
        } else {
          Cf[(size_t)m * N + col] = o;
        }
      }
    }
  }
}

// ---------------------------------------------------------------------------
// MFMA flash attention, split-bf16 (3-pass) — unchanged from round 2.
// ---------------------------------------------------------------------------
__global__ __launch_bounds__(256) void attn_mfma(const unsigned short* __restrict__ qkvh,
                                                 const unsigned short* __restrict__ qkvl,
                                                 float* __restrict__ out) {
  __shared__ __align__(16) unsigned short Vth[64][72];
  __shared__ __align__(16) unsigned short Vtl[64][72];
  __shared__ __align__(16) unsigned short Ph[4][16][72];
  __shared__ __align__(16) unsigned short Pl[4][16][72];
  const int tid = threadIdx.x;
  const int w = tid >> 6, l = tid & 63;
  const int lr = l & 15, lg = l >> 4;
  const int q0 = blockIdx.x * 64;
  const int b = blockIdx.y >> 4, h = blockIdx.y & 15;
  const size_t bbase = (size_t)b * 2048;

  const size_t qrow = (bbase + q0 + w * 16 + lr) * 3072 + h * 64;
  bfrag qh[2], ql[2];
#pragma unroll
  for (int dc = 0; dc < 2; ++dc) {
    qh[dc] = *reinterpret_cast<const bfrag*>(qkvh + qrow + dc * 32 + lg * 8);
    ql[dc] = *reinterpret_cast<const bfrag*>(qkvl + qrow + dc * 32 + lg * 8);
  }

  f4 oacc[4];
  float m_i[4], l_i[4];
#pragma unroll
  for (int i = 0; i < 4; ++i) {
    m_i[i] = -1e30f;
    l_i[i] = 0.f;
#pragma unroll
    for (int j = 0; j < 4; ++j) oacc[i][j] = 0.f;
  }

  for (int kt = 0; kt < 32; ++kt) {
    const size_t krow = bbase + (size_t)kt * 64;
    __syncthreads();
    {
      const size_t vrow = (krow + l) * 3072 + 2048 + h * 64 + w * 16;
      bfrag vh0 = *reinterpret_cast<const bfrag*>(qkvh + vrow);
      bfrag vh1 = *reinterpret_cast<const bfrag*>(qkvh + vrow + 8);
      bfrag vl0 = *reinterpret_cast<const bfrag*>(qkvl + vrow);
      bfrag vl1 = *reinterpret_cast<const bfrag*>(qkvl + vrow + 8);
#pragma unroll
      for (int j = 0; j < 8; ++j) {
        Vth[w * 16 + j][l]     = (unsigned short)vh0[j];
        Vth[w * 16 + 8 + j][l] = (unsigned short)vh1[j];
        Vtl[w * 16 + j][l]     = (unsigned short)vl0[j];
        Vtl[w * 16 + 8 + j][l] = (unsigned short)vl1[j];
      }
    }
    __syncthreads();

    f4 sacc[4];
#pragma unroll
    for (int ks = 0; ks < 4; ++ks)
#pragma unroll
      for (int j = 0; j < 4; ++j) sacc[ks][j] = 0.f;
#pragma unroll
    for (int ks = 0; ks < 4; ++ks) {
      const size_t kr = (krow + ks * 16 + lr) * 3072 + 1024 + h * 64;
#pragma unroll
      for (int dc = 0; dc < 2; ++dc) {
        bfrag kh = *reinterpret_cast<const bfrag*>(qkvh + kr + dc * 32 + lg * 8);
        bfrag kl = *reinterpret_cast<const bfrag*>(qkvl + kr + dc * 32 + lg * 8);
        sacc[ks] = MFMA16(qh[dc], kh, sacc[ks]);
        sacc[ks] = MFMA16(qh[dc], kl, sacc[ks]);
        sacc[ks] = MFMA16(ql[dc], kh, sacc[ks]);
      }
    }

#pragma unroll
    for (int r = 0; r < 4; ++r) {
      float s0 = sacc[0][r] * 0.125f, s1 = sacc[1][r] * 0.125f;
      float s2 = sacc[2][r] * 0.125f, s3 = sacc[3][r] * 0.125f;
      float mt = fmaxf(fmaxf(s0, s1), fmaxf(s2, s3));
#pragma unroll
      for (int d = 1; d < 16; d <<= 1) mt = fmaxf(mt, __shfl_xor(mt, d));
      float mn = fmaxf(m_i[r], mt);
      float corr = __expf(m_i[r] - mn);
      float p0 = __expf(s0 - mn), p1 = __expf(s1 - mn);
      float p2 = __expf(s2 - mn), p3 = __expf(s3 - mn);
      float rs = (p0 + p1) + (p2 + p3);
#pragma unroll
      for (int d = 1; d < 16; d <<= 1) rs += __shfl_xor(rs, d);
      m_i[r] = mn;
      l_i[r] = l_i[r] * corr + rs;
#pragma unroll
      for (int ds = 0; ds < 4; ++ds) oacc[ds][r] *= corr;
      float pa[4] = {p0, p1, p2, p3};
#pragma unroll
      for (int ks = 0; ks < 4; ++ks) {
        unsigned short hh = f2bf(pa[ks]);
        Ph[w][lg * 4 + r][ks * 16 + lr] = hh;
        Pl[w][lg * 4 + r][ks * 16 + lr] = f2bf(pa[ks] - bf2f(hh));
      }
    }

#pragma unroll
    for (int kc = 0; kc < 2; ++kc) {
      bfrag pah = *reinterpret_cast<const bfrag*>(&Ph[w][lr][kc * 32 + lg * 8]);
      bfrag pal = *reinterpret_cast<const bfrag*>(&Pl[w][lr][kc * 32 + lg * 8]);
#pragma unroll
      for (int ds = 0; ds < 4; ++ds) {
        bfrag vbh = *reinterpret_cast<const bfrag*>(&Vth[ds * 16 + lr][kc * 32 + lg * 8]);
        bfrag vbl = *reinterpret_cast<const bfrag*>(&Vtl[ds * 16 + lr][kc * 32 + lg * 8]);
        oacc[ds] = MFMA16(pah, vbh, oacc[ds]);
        oacc[ds] = MFMA16(pah, vbl, oacc[ds]);
        oacc[ds] = MFMA16(pal, vbh, oacc[ds]);
      }
    }
  }

#pragma unroll
  for (int r = 0; r < 4; ++r) {
    float inv = 1.0f / l_i[r];
    size_t orow = (bbase + q0 + w * 16 + lg * 4 + r) * 1024 + h * 64 + lr;
#pragma unroll
    for (int ds = 0; ds < 4; ++ds) out[orow + ds * 16] = oacc[ds][r] * inv;
  }
}

// ---------------------------------------------------------------------------
// Workspace layout (72.25 MiB):
//   @ 0        : x_q  bf16 [4096,1024] (8 MiB)  — reused as x2_q after QKV
//   @ 8 MiB    : s_x  fp32 [4096,8] (128 KiB)   — reused as s2
//   @ 8.25 MiB : WTqkv_h bf16 [3072,1024] (6 MiB)
//   @ 14.25    : WTqkv_l (6 MiB)
//   @ 20.25    : WTout_h bf16 [1024,1024] (2 MiB)
//   @ 22.25    : WTout_l (2 MiB)
//   @ 24.25    : qkvh bf16 [4096,3072] (24 MiB)
//   @ 48.25    : qkvl (24 MiB)
// ---------------------------------------------------------------------------
extern "C" void kernel_launch(void* const* d_in, const int* in_sizes, int n_in,
                              void* d_out, int out_size, void* d_ws, size_t ws_size,
                              hipStream_t stream) {
  const float* x     = (const float*)d_in[0];
  const float* W_qkv = (const float*)d_in[1];
  const float* b_qkv = (const float*)d_in[2];
  const float* W_out = (const float*)d_in[3];
  const float* b_out = (const float*)d_in[4];
  float* y = (float*)d_out;

  char* ws = (char*)d_ws;
  const size_t MB = 1u << 20;
  unsigned short* x_q   = (unsigned short*)(ws);
  float*          s_x   = (float*)(ws + 8 * MB);
  unsigned short* wqh   = (unsigned short*)(ws + 8 * MB + 256 * 1024);
  unsigned short* wql   = (unsigned short*)(ws + 14 * MB + 256 * 1024);
  unsigned short* woh   = (unsigned short*)(ws + 20 * MB + 256 * 1024);
  unsigned short* wol   = (unsigned short*)(ws + 22 * MB + 256 * 1024);
  unsigned short* qkvh  = (unsigned short*)(ws + 24 * MB + 256 * 1024);
  unsigned short* qkvl  = (unsigned short*)(ws + 48 * MB + 256 * 1024);

  // 1. quantize activations (codes + scales) and weights (split + transpose)
  quant_x<<<8192, 256, 0, stream>>>(x, x_q, s_x, 32768);
  quant_w_t<<<dim3(24, 16), 256, 0, stream>>>(W_qkv, wqh, wql, 1024, 3072);
  quant_w_t<<<dim3(8, 16), 256, 0, stream>>>(W_out, woh, wol, 1024, 1024);

  // 2. QKV projection (quant-aware MFMA) -> split bf16 hi/lo
  gemm_q<true><<<768, 256, 0, stream>>>(x_q, s_x, wqh, wql, b_qkv,
                                        nullptr, qkvh, qkvl, 4096, 3072, 1024);

  // 3. MFMA flash attention -> d_out [B,S,H*Dh] fp32
  attn_mfma<<<dim3(32, 32), 256, 0, stream>>>(qkvh, qkvl, y);

  // 4. quantize attention output (reuse x_q / s_x buffers)
  quant_x<<<8192, 256, 0, stream>>>(y, x_q, s_x, 32768);

  // 5. output projection (quant-aware MFMA) -> fp32 d_out
  gemm_q<false><<<256, 256, 0, stream>>>(x_q, s_x, woh, wol, b_out,
                                         y, nullptr, nullptr, 4096, 1024, 1024);
}

// Round 4
// 345.409 us; speedup vs baseline: 3.1653x; 1.3957x over previous
//
#include <hip/hip_runtime.h>
#include <cstdint>
#include <cstddef>

typedef __attribute__((ext_vector_type(8))) short bfrag;    // 8 bf16 (4 VGPR)
typedef __attribute__((ext_vector_type(4))) float f4;       // 16x16 MFMA C/D
typedef __attribute__((ext_vector_type(16))) float f16v;    // 32x32 MFMA C/D
typedef __attribute__((ext_vector_type(4))) unsigned short us4;

#define MFMA16(a, b, c) __builtin_amdgcn_mfma_f32_16x16x32_bf16(a, b, c, 0, 0, 0)
#define MFMA32(a, b, c) __builtin_amdgcn_mfma_f32_32x32x16_bf16(a, b, c, 0, 0, 0)

// ---------------------------------------------------------------------------
// fp32 -> bf16 RNE, and hi/lo split helpers
// ---------------------------------------------------------------------------
__device__ __forceinline__ unsigned short f2bf(float x) {
  unsigned u = __float_as_uint(x);
  u += 0x7fffu + ((u >> 16) & 1u);
  return (unsigned short)(u >> 16);
}
__device__ __forceinline__ float bf2f(unsigned short h) {
  return __uint_as_float(((unsigned)h) << 16);
}

// ---------------------------------------------------------------------------
// Software-exact OCP e4m3fn rounding (RTNE via magic-add; matches ml_dtypes
// bit-exact incl. subnormal grid 2^-9 and the 448-saturation region).
// ---------------------------------------------------------------------------
__device__ __forceinline__ float qd_e4m3(float v) {
  float a = fabsf(v);
  unsigned u = __float_as_uint(a);
  int e = (int)(u >> 23) - 127;
  int k = e - 3;
  if (k < -9) k = -9;
  float big = __uint_as_float((unsigned)(k + 150) << 23);  // 2^(k+23)
  float r = (a + big) - big;
  return __builtin_copysignf(r, v);
}

// ---------------------------------------------------------------------------
// Activation quant: per 128-block, emit e4m3 CODES as bf16 (exact) + scale.
// ---------------------------------------------------------------------------
__global__ __launch_bounds__(256) void quant_x(const float* __restrict__ src,
                                               unsigned short* __restrict__ q,
                                               float* __restrict__ s,
                                               int nblk) {
  int gid = blockIdx.x * 256 + threadIdx.x;
  int wid = gid >> 6;
  int lane = gid & 63;
  if (wid >= nblk) return;
  size_t off = (size_t)wid * 128 + lane * 2;
  float2 xv = *reinterpret_cast<const float2*>(src + off);
  float m = fmaxf(fabsf(xv.x), fabsf(xv.y));
#pragma unroll
  for (int d = 32; d > 0; d >>= 1) m = fmaxf(m, __shfl_xor(m, d));
  float scale = fmaxf(m / 448.0f, 1e-12f);
  unsigned short q0 = f2bf(qd_e4m3(xv.x / scale));  // exact: e4m3 ⊂ bf16
  unsigned short q1 = f2bf(qd_e4m3(xv.y / scale));
  *reinterpret_cast<unsigned*>(q + off) = (unsigned)q0 | ((unsigned)q1 << 16);
  if (lane == 0) s[wid] = scale;
}

// ---------------------------------------------------------------------------
// Weight quant + dequant + hi/lo split + TRANSPOSE: W[K,N] -> WTh/WTl[N,K].
// ---------------------------------------------------------------------------
__global__ __launch_bounds__(256) void quant_w_t(const float* __restrict__ W,
                                                 unsigned short* __restrict__ WTh,
                                                 unsigned short* __restrict__ WTl,
                                                 int K, int N) {
  __shared__ __align__(16) unsigned short Ht[128][72];
  __shared__ __align__(16) unsigned short Lt[128][72];
  const int tid = threadIdx.x;
  const int w = tid >> 6, l = tid & 63;
  const int k0 = blockIdx.y * 64, n0 = blockIdx.x * 128;
#pragma unroll 4
  for (int i = 0; i < 16; ++i) {
    int kl = w * 16 + i;
    float2 xv = *reinterpret_cast<const float2*>(&W[(size_t)(k0 + kl) * N + n0 + l * 2]);
    float m = fmaxf(fabsf(xv.x), fabsf(xv.y));
#pragma unroll
    for (int d = 32; d > 0; d >>= 1) m = fmaxf(m, __shfl_xor(m, d));
    float scale = fmaxf(m / 448.0f, 1e-12f);
    float d0 = qd_e4m3(xv.x / scale) * scale;
    float d1 = qd_e4m3(xv.y / scale) * scale;
    unsigned short h0 = f2bf(d0), h1 = f2bf(d1);
    Ht[l * 2][kl] = h0;
    Ht[l * 2 + 1][kl] = h1;
    Lt[l * 2][kl] = f2bf(d0 - bf2f(h0));
    Lt[l * 2 + 1][kl] = f2bf(d1 - bf2f(h1));
  }
  __syncthreads();
  const int arr = tid >> 7, n = tid & 127;
  const unsigned short(*T)[72] = arr ? Lt : Ht;
  unsigned short* dst = (arr ? WTl : WTh) + (size_t)(n0 + n) * K + k0;
#pragma unroll
  for (int j = 0; j < 8; ++j)
    *reinterpret_cast<bfrag*>(dst + j * 8) = *reinterpret_cast<const bfrag*>(&T[n][j * 8]);
}

// ---------------------------------------------------------------------------
// Quantization-aware MFMA GEMM (unchanged from round 3).
// ---------------------------------------------------------------------------
template <bool SPLIT>
__global__ __launch_bounds__(256, 2) void gemm_q(const unsigned short* __restrict__ Aq,
                                                 const float* __restrict__ As,
                                                 const unsigned short* __restrict__ WTh,
                                                 const unsigned short* __restrict__ WTl,
                                                 const float* __restrict__ bias,
                                                 float* __restrict__ Cf,
                                                 unsigned short* __restrict__ Ch,
                                                 unsigned short* __restrict__ Cl,
                                                 int M, int N, int K) {
  __shared__ __align__(16) unsigned short Al[128][72];
  __shared__ __align__(16) unsigned short Bh[128][72];
  __shared__ __align__(16) unsigned short Bl[128][72];
  __shared__ float Ss[128][8];
  const int tid = threadIdx.x;
  const int w = tid >> 6, l = tid & 63;
  const int lr = l & 15, lg = l >> 4;
  const int nbx = N >> 7;
  const int nwg = nbx * (M >> 7);
  const int q8 = nwg >> 3;
  const int swz = ((int)blockIdx.x & 7) * q8 + ((int)blockIdx.x >> 3);
  const int row0 = (swz / nbx) << 7, col0 = (swz % nbx) << 7;
  const int wr = (w >> 1) * 64, wc = (w & 1) * 64;

  {
    int r = tid >> 1, c0 = (tid & 1) * 4;
    *reinterpret_cast<float4*>(&Ss[r][c0]) =
        *reinterpret_cast<const float4*>(&As[(size_t)(row0 + r) * 8 + c0]);
  }

  f4 acc[4][4], seg[4][4];
#pragma unroll
  for (int i = 0; i < 4; ++i)
#pragma unroll
    for (int j = 0; j < 4; ++j)
#pragma unroll
      for (int c = 0; c < 4; ++c) {
        acc[i][j][c] = 0.f;
        seg[i][j][c] = 0.f;
      }

  const int sr = tid >> 1, sko = (tid & 1) * 32;
  const unsigned short* gA = Aq + (size_t)(row0 + sr) * K + sko;
  const unsigned short* gH = WTh + (size_t)(col0 + sr) * K + sko;
  const unsigned short* gL = WTl + (size_t)(col0 + sr) * K + sko;

  const int niter = K >> 6;
  for (int it = 0; it < niter; ++it) {
    const int k0 = it << 6;
    __syncthreads();
#pragma unroll
    for (int j = 0; j < 4; ++j) {
      *reinterpret_cast<bfrag*>(&Al[sr][sko + j * 8]) =
          *reinterpret_cast<const bfrag*>(gA + k0 + j * 8);
      *reinterpret_cast<bfrag*>(&Bh[sr][sko + j * 8]) =
          *reinterpret_cast<const bfrag*>(gH + k0 + j * 8);
      *reinterpret_cast<bfrag*>(&Bl[sr][sko + j * 8]) =
          *reinterpret_cast<const bfrag*>(gL + k0 + j * 8);
    }
    __syncthreads();

#pragma unroll
    for (int ks = 0; ks < 2; ++ks) {
      bfrag af[4];
#pragma unroll
      for (int mf = 0; mf < 4; ++mf)
        af[mf] = *reinterpret_cast<const bfrag*>(&Al[wr + mf * 16 + lr][ks * 32 + lg * 8]);
#pragma unroll
      for (int nf = 0; nf < 4; ++nf) {
        bfrag bh = *reinterpret_cast<const bfrag*>(&Bh[wc + nf * 16 + lr][ks * 32 + lg * 8]);
        bfrag bl = *reinterpret_cast<const bfrag*>(&Bl[wc + nf * 16 + lr][ks * 32 + lg * 8]);
#pragma unroll
        for (int mf = 0; mf < 4; ++mf) {
          seg[mf][nf] = MFMA16(af[mf], bh, seg[mf][nf]);
          seg[mf][nf] = MFMA16(af[mf], bl, seg[mf][nf]);
        }
      }
    }

    if (it & 1) {
      const int kb = it >> 1;
#pragma unroll
      for (int mf = 0; mf < 4; ++mf) {
        float sv[4];
#pragma unroll
        for (int r = 0; r < 4; ++r) sv[r] = Ss[wr + mf * 16 + lg * 4 + r][kb];
#pragma unroll
        for (int nf = 0; nf < 4; ++nf)
#pragma unroll
          for (int r = 0; r < 4; ++r) {
            acc[mf][nf][r] += sv[r] * seg[mf][nf][r];
            seg[mf][nf][r] = 0.f;
          }
      }
    }
  }

#pragma unroll
  for (int mf = 0; mf < 4; ++mf) {
#pragma unroll
    for (int r = 0; r < 4; ++r) {
      const int m = row0 + wr + mf * 16 + lg * 4 + r;
#pragma unroll
      for (int nf = 0; nf < 4; ++nf) {
        const int col = col0 + wc + nf * 16 + lr;
        float o = acc[mf][nf][r] + bias[col];
        if (SPLIT) {
          unsigned short hh = f2bf(o);
          Ch[(size_t)m * N + col] = hh;
          Cl[(size_t)m * N + col] = f2bf(o - bf2f(hh));
        } else {
          Cf[(size_t)m * N + col] = o;
        }
      }
    }
  }
}

// ---------------------------------------------------------------------------
// Swapped-operand 32x32 MFMA flash attention, split-bf16 3-pass.
// Grid (S/128=16, B*H=32); 256 thr = 4 waves; wave owns 32 q-rows (q=lane&31).
// QK^T swapped: S^T = mfma32(K, Q)  -> lane holds P-row (q=l&31) over 32 k's.
// Softmax fully in-lane + one shfl_xor(32). P-frags built in-register.
// PV swapped: O^T = mfma32(V^T, P). Only V^T staged in LDS (double-buffered,
// one barrier/iter, rotation-swizzled conflict-free staging writes).
// C/D map (m74/m101): col=lane&31, row=(reg&3)+8*(reg>>2)+4*(lane>>5).
// A/B map: row/col=lane&31, k=(lane>>5)*8+e.
// ---------------------------------------------------------------------------
__global__ __launch_bounds__(256, 2) void attn_mfma32(const unsigned short* __restrict__ qkvh,
                                                      const unsigned short* __restrict__ qkvl,
                                                      float* __restrict__ out) {
  __shared__ __align__(16) unsigned short Vth[2][64][40];  // V^T: [buf][d][kpos]
  __shared__ __align__(16) unsigned short Vtl[2][64][40];
  const int tid = threadIdx.x;
  const int w = tid >> 6, l = tid & 63;
  const int q = l & 31;        // lane's q-row / V^T d-row / K k-row
  const int hi = l >> 5;
  const int q0 = blockIdx.x * 128 + w * 32;
  const int b = blockIdx.y >> 4, h = blockIdx.y & 15;
  const size_t bbase = (size_t)b * 2048;
  const size_t hoff = (size_t)h * 64;

  // Q fragments (hoisted): B-operand, lane = col q, k-dim d = 16f + 8*hi + e
  bfrag qh[4], ql[4];
  {
    const size_t qrow = (bbase + q0 + q) * 3072 + hoff + hi * 8;
#pragma unroll
    for (int f = 0; f < 4; ++f) {
      qh[f] = *reinterpret_cast<const bfrag*>(qkvh + qrow + f * 16);
      ql[f] = *reinterpret_cast<const bfrag*>(qkvl + qrow + f * 16);
    }
  }

  // V staging role: thread -> (kpos, d-chunk)
  const int skp = tid >> 3;      // 0..31
  const int sc = tid & 7;        // 0..7 (d-chunk of 8)

  bfrag kh[4], kl[4];            // K frags for current tile (A-operand)
  bfrag svh, svl;                // V staging registers (next tile)

  // ---- prologue: K(0), V(0) ----
  {
    const size_t kr = (bbase + 0 + q) * 3072 + 1024 + hoff + hi * 8;
#pragma unroll
    for (int f = 0; f < 4; ++f) {
      kh[f] = *reinterpret_cast<const bfrag*>(qkvh + kr + f * 16);
      kl[f] = *reinterpret_cast<const bfrag*>(qkvl + kr + f * 16);
    }
    const size_t vr = (bbase + 0 + skp) * 3072 + 2048 + hoff + sc * 8;
    svh = *reinterpret_cast<const bfrag*>(qkvh + vr);
    svl = *reinterpret_cast<const bfrag*>(qkvl + vr);
#pragma unroll
    for (int j = 0; j < 8; ++j) {  // rotated scatter: conflict-free
      int jj = (j + sc) & 7;
      Vth[0][sc * 8 + jj][skp] = (unsigned short)svh[jj];
      Vtl[0][sc * 8 + jj][skp] = (unsigned short)svl[jj];
    }
  }
  __syncthreads();

  f16v oacc0, oacc1;
#pragma unroll
  for (int r = 0; r < 16; ++r) { oacc0[r] = 0.f; oacc1[r] = 0.f; }
  float m_i = -1e30f, l_i = 0.f;

  for (int kt = 0; kt < 64; ++kt) {
    const int cur = kt & 1;

    // ---- QK^T (swapped): S^T[k][q], 3-pass split ----
    f16v s;
#pragma unroll
    for (int r = 0; r < 16; ++r) s[r] = 0.f;
#pragma unroll
    for (int f = 0; f < 4; ++f) s = MFMA32(kh[f], qh[f], s);
#pragma unroll
    for (int f = 0; f < 4; ++f) s = MFMA32(kh[f], ql[f], s);
#pragma unroll
    for (int f = 0; f < 4; ++f) s = MFMA32(kl[f], qh[f], s);

    // prefetch K for next tile (regs free after the MFMAs above)
    if (kt < 63) {
      const size_t kr = (bbase + (kt + 1) * 32 + q) * 3072 + 1024 + hoff + hi * 8;
#pragma unroll
      for (int f = 0; f < 4; ++f) {
        kh[f] = *reinterpret_cast<const bfrag*>(qkvh + kr + f * 16);
        kl[f] = *reinterpret_cast<const bfrag*>(qkvl + kr + f * 16);
      }
    }

    // ---- online softmax, in-lane (q = l&31); k = (r&3)+8*(r>>2)+4*hi ----
    float p[16];
#pragma unroll
    for (int r = 0; r < 16; ++r) p[r] = s[r] * 0.125f;
    float mt = p[0];
#pragma unroll
    for (int r = 1; r < 16; ++r) mt = fmaxf(mt, p[r]);
    mt = fmaxf(mt, __shfl_xor(mt, 32));
    float mn = fmaxf(m_i, mt);
    float corr = __expf(m_i - mn);
    float rs = 0.f;
#pragma unroll
    for (int r = 0; r < 16; ++r) {
      p[r] = __expf(p[r] - mn);
      rs += p[r];
    }
    rs += __shfl_xor(rs, 32);
    m_i = mn;
    l_i = l_i * corr + rs;
#pragma unroll
    for (int r = 0; r < 16; ++r) { oacc0[r] *= corr; oacc1[r] *= corr; }

    // prefetch V stage for next tile
    if (kt < 63) {
      const size_t vr = (bbase + (kt + 1) * 32 + skp) * 3072 + 2048 + hoff + sc * 8;
      svh = *reinterpret_cast<const bfrag*>(qkvh + vr);
      svl = *reinterpret_cast<const bfrag*>(qkvl + vr);
    }

    // ---- pack P hi/lo and build PV B-frags in-register ----
    unsigned ph_[8], pl_[8], sh_[8], sl_[8];
#pragma unroll
    for (int i = 0; i < 8; ++i) {
      unsigned short h0 = f2bf(p[2 * i]), h1 = f2bf(p[2 * i + 1]);
      ph_[i] = (unsigned)h0 | ((unsigned)h1 << 16);
      unsigned short g0 = f2bf(p[2 * i] - bf2f(h0));
      unsigned short g1 = f2bf(p[2 * i + 1] - bf2f(h1));
      pl_[i] = (unsigned)g0 | ((unsigned)g1 << 16);
    }
#pragma unroll
    for (int i = 0; i < 8; ++i) {
      sh_[i] = __shfl_xor(ph_[i], 32);
      sl_[i] = __shfl_xor(pl_[i], 32);
    }
    union U4 { unsigned u[4]; bfrag f; };
    U4 f0h, f1h, f0l, f1l;
    if (hi) {
      f0h.u[0] = sh_[2]; f0h.u[1] = sh_[3]; f0h.u[2] = ph_[2]; f0h.u[3] = ph_[3];
      f1h.u[0] = sh_[6]; f1h.u[1] = sh_[7]; f1h.u[2] = ph_[6]; f1h.u[3] = ph_[7];
      f0l.u[0] = sl_[2]; f0l.u[1] = sl_[3]; f0l.u[2] = pl_[2]; f0l.u[3] = pl_[3];
      f1l.u[0] = sl_[6]; f1l.u[1] = sl_[7]; f1l.u[2] = pl_[6]; f1l.u[3] = pl_[7];
    } else {
      f0h.u[0] = ph_[0]; f0h.u[1] = ph_[1]; f0h.u[2] = sh_[0]; f0h.u[3] = sh_[1];
      f1h.u[0] = ph_[4]; f1h.u[1] = ph_[5]; f1h.u[2] = sh_[4]; f1h.u[3] = sh_[5];
      f0l.u[0] = pl_[0]; f0l.u[1] = pl_[1]; f0l.u[2] = sl_[0]; f0l.u[3] = sl_[1];
      f1l.u[0] = pl_[4]; f1l.u[1] = pl_[5]; f1l.u[2] = sl_[4]; f1l.u[3] = sl_[5];
    }

    // ---- PV (swapped): O^T[d][q] += V^T · P, 3-pass split ----
#pragma unroll
    for (int dblk = 0; dblk < 2; ++dblk) {
#pragma unroll
      for (int c = 0; c < 2; ++c) {
        bfrag vh_ = *reinterpret_cast<const bfrag*>(&Vth[cur][dblk * 32 + q][c * 16 + hi * 8]);
        bfrag vl_ = *reinterpret_cast<const bfrag*>(&Vtl[cur][dblk * 32 + q][c * 16 + hi * 8]);
        bfrag pF = c ? f1h.f : f0h.f;
        bfrag pL = c ? f1l.f : f0l.f;
        if (dblk == 0) {
          oacc0 = MFMA32(vh_, pF, oacc0);
          oacc0 = MFMA32(vh_, pL, oacc0);
          oacc0 = MFMA32(vl_, pF, oacc0);
        } else {
          oacc1 = MFMA32(vh_, pF, oacc1);
          oacc1 = MFMA32(vh_, pL, oacc1);
          oacc1 = MFMA32(vl_, pF, oacc1);
        }
      }
    }

    // ---- write staged V(kt+1) into the other buffer ----
    if (kt < 63) {
#pragma unroll
      for (int j = 0; j < 8; ++j) {
        int jj = (j + sc) & 7;
        Vth[cur ^ 1][sc * 8 + jj][skp] = (unsigned short)svh[jj];
        Vtl[cur ^ 1][sc * 8 + jj][skp] = (unsigned short)svl[jj];
      }
    }
    __syncthreads();
  }

  // ---- epilogue: normalize (in-lane), store fp32 [B,S,H*Dh] ----
  float inv = 1.0f / l_i;
  const size_t orow = (bbase + q0 + q) * 1024 + hoff;
#pragma unroll
  for (int dblk = 0; dblk < 2; ++dblk) {
#pragma unroll
    for (int rg = 0; rg < 4; ++rg) {
      float4 o;
      if (dblk == 0) {
        o.x = oacc0[rg * 4 + 0] * inv; o.y = oacc0[rg * 4 + 1] * inv;
        o.z = oacc0[rg * 4 + 2] * inv; o.w = oacc0[rg * 4 + 3] * inv;
      } else {
        o.x = oacc1[rg * 4 + 0] * inv; o.y = oacc1[rg * 4 + 1] * inv;
        o.z = oacc1[rg * 4 + 2] * inv; o.w = oacc1[rg * 4 + 3] * inv;
      }
      *reinterpret_cast<float4*>(out + orow + dblk * 32 + rg * 8 + hi * 4) = o;
    }
  }
}

// ---------------------------------------------------------------------------
// Workspace layout (72.25 MiB) — unchanged from round 3.
// ---------------------------------------------------------------------------
extern "C" void kernel_launch(void* const* d_in, const int* in_sizes, int n_in,
                              void* d_out, int out_size, void* d_ws, size_t ws_size,
                              hipStream_t stream) {
  const float* x     = (const float*)d_in[0];
  const float* W_qkv = (const float*)d_in[1];
  const float* b_qkv = (const float*)d_in[2];
  const float* W_out = (const float*)d_in[3];
  const float* b_out = (const float*)d_in[4];
  float* y = (float*)d_out;

  char* ws = (char*)d_ws;
  const size_t MB = 1u << 20;
  unsigned short* x_q   = (unsigned short*)(ws);
  float*          s_x   = (float*)(ws + 8 * MB);
  unsigned short* wqh   = (unsigned short*)(ws + 8 * MB + 256 * 1024);
  unsigned short* wql   = (unsigned short*)(ws + 14 * MB + 256 * 1024);
  unsigned short* woh   = (unsigned short*)(ws + 20 * MB + 256 * 1024);
  unsigned short* wol   = (unsigned short*)(ws + 22 * MB + 256 * 1024);
  unsigned short* qkvh  = (unsigned short*)(ws + 24 * MB + 256 * 1024);
  unsigned short* qkvl  = (unsigned short*)(ws + 48 * MB + 256 * 1024);

  // 1. quantize activations (codes + scales) and weights (split + transpose)
  quant_x<<<8192, 256, 0, stream>>>(x, x_q, s_x, 32768);
  quant_w_t<<<dim3(24, 16), 256, 0, stream>>>(W_qkv, wqh, wql, 1024, 3072);
  quant_w_t<<<dim3(8, 16), 256, 0, stream>>>(W_out, woh, wol, 1024, 1024);

  // 2. QKV projection (quant-aware MFMA) -> split bf16 hi/lo
  gemm_q<true><<<768, 256, 0, stream>>>(x_q, s_x, wqh, wql, b_qkv,
                                        nullptr, qkvh, qkvl, 4096, 3072, 1024);

  // 3. swapped 32x32 MFMA flash attention -> d_out [B,S,H*Dh] fp32
  attn_mfma32<<<dim3(16, 32), 256, 0, stream>>>(qkvh, qkvl, y);

  // 4. quantize attention output (reuse x_q / s_x buffers)
  quant_x<<<8192, 256, 0, stream>>>(y, x_q, s_x, 32768);

  // 5. output projection (quant-aware MFMA) -> fp32 d_out
  gemm_q<false><<<256, 256, 0, stream>>>(x_q, s_x, woh, wol, b_out,
                                         y, nullptr, nullptr, 4096, 1024, 1024);
}